// Round 10
// baseline (67.079 us; speedup 1.0000x reference)
//
#include <hip/hip_runtime.h>

#define ALPHA_C    0.5f
#define C_CLASSES  100000
#define D          128
#define BATCH      131072
#define CHUNK      2048
#define NB         ((C_CLASSES + CHUNK - 1) / CHUNK)   // 49 scan blocks
#define NPAIR      (C_CLASSES / 2)                     // 50000 class-pairs
#define PBLOCKS    2048                                // 8 blocks/CU -> 8192 waves

// ---------------------------------------------------------------------------
// DPP 32-lane group reduce (VALU-speed). row_shr 1,2,4,8 then bcast15:
// lane 31 = sum of lanes 0..31, lane 63 = sum of lanes 32..63.
// ---------------------------------------------------------------------------
template<int CTRL, int RMASK>
__device__ __forceinline__ float dpp_add(float x) {
    int v = __builtin_amdgcn_update_dpp(0, __float_as_int(x), CTRL, RMASK, 0xF, true);
    return x + __int_as_float(v);
}
__device__ __forceinline__ float group_sum(float ss) {
    ss = dpp_add<0x111, 0xF>(ss);   // row_shr:1
    ss = dpp_add<0x112, 0xF>(ss);   // row_shr:2
    ss = dpp_add<0x114, 0xF>(ss);   // row_shr:4
    ss = dpp_add<0x118, 0xF>(ss);   // row_shr:8
    ss = dpp_add<0x142, 0xA>(ss);   // row_bcast15 -> rows 1,3
    return ss;                      // lane31 / lane63 hold the 32-lane sums
}

// ---------------------------------------------------------------------------
// K1: label histogram (counts array == cnt_cur, zeroed by memset)
// ---------------------------------------------------------------------------
__global__ void hist_kernel(const int* __restrict__ labels,
                            int* __restrict__ counts) {
    int i = blockIdx.x * blockDim.x + threadIdx.x;   // grid == BATCH exactly
    atomicAdd(&counts[labels[i]], 1);
}

// ---------------------------------------------------------------------------
// K2: per-chunk exclusive scan of counts -> meta {excl_in_chunk, n, 0, 0}
// ---------------------------------------------------------------------------
__global__ __launch_bounds__(256)
void scan1_kernel(const int* __restrict__ counts,
                  int4* __restrict__ meta,
                  int* __restrict__ blockSums) {
    __shared__ int sdata[256];
    const int tid  = threadIdx.x;
    const int base = blockIdx.x * CHUNK + tid * 8;
    int v[8]; int s = 0;
    #pragma unroll
    for (int j = 0; j < 8; ++j) {
        int idx = base + j;
        v[j] = (idx < C_CLASSES) ? counts[idx] : 0;
        s += v[j];
    }
    sdata[tid] = s;
    __syncthreads();
    #pragma unroll
    for (int off = 1; off < 256; off <<= 1) {
        int t = (tid >= off) ? sdata[tid - off] : 0;
        __syncthreads();
        sdata[tid] += t;
        __syncthreads();
    }
    int excl = sdata[tid] - s;
    #pragma unroll
    for (int j = 0; j < 8; ++j) {
        int idx = base + j;
        if (idx < C_CLASSES) meta[idx] = make_int4(excl, v[j], 0, 0);
        excl += v[j];
    }
    if (tid == 255) blockSums[blockIdx.x] = sdata[255];
}

// ---------------------------------------------------------------------------
// K3: finalize meta.x (+= chunk offset, computed in-block by wave reduce of
// blockSums[0..blk-1]); seed cursor. scan2 kernel is folded in here.
// ---------------------------------------------------------------------------
__global__ __launch_bounds__(256)
void addoff_kernel(int4* __restrict__ meta,
                   const int* __restrict__ blockSums,
                   int* __restrict__ cursor) {
    __shared__ int s_off;
    const int tid = threadIdx.x;
    if (tid < 64) {
        int v = (tid < NB && tid < (int)blockIdx.x) ? blockSums[tid] : 0;
        #pragma unroll
        for (int off = 32; off; off >>= 1) v += __shfl_xor(v, off);
        if (tid == 0) s_off = v;
    }
    __syncthreads();
    const int off  = s_off;
    const int base = blockIdx.x * CHUNK + tid * 8;
    #pragma unroll
    for (int j = 0; j < 8; ++j) {
        int idx = base + j;
        if (idx < C_CLASSES) {
            int st = meta[idx].x + off;
            meta[idx].x = st;
            cursor[idx] = st;
        }
    }
}

// ---------------------------------------------------------------------------
// K4: scatter sample indices into class buckets; seed meta.z/.w with the
// first two sample indices of each class (removes the order-load hop for
// n<=2 classes, 85%). rel is unique per class -> no write race.
// ---------------------------------------------------------------------------
__global__ void scatter_kernel(const int* __restrict__ labels,
                               int* __restrict__ cursor,
                               int* __restrict__ order,
                               int* __restrict__ meta_raw) {   // int view of meta
    int b = blockIdx.x * blockDim.x + threadIdx.x;   // grid == BATCH exactly
    const int l   = labels[b];
    const int pos = atomicAdd(&cursor[l], 1);
    order[pos] = b;
    const int start = meta_raw[4 * l];               // finalized by addoff
    const int rel   = pos - start;
    if (rel < 2) meta_raw[4 * l + 2 + rel] = b;      // .z or .w
}

// ---------------------------------------------------------------------------
// K5 (R10): PERSISTENT dim-major fused kernel. 2048 blocks (8/CU), each wave
// owns one class-pair slot and grid-strides (~6 iterations). At the top of
// each iteration it issues NEXT pair's meta+center loads (loop-carried ->
// regalloc must keep them live; defeats the R4-R7 serialization), then
// consumes the CURRENT pair whose meta is already resident: feature rows
// f0/f1 load directly from meta.z/.w (no order hop for n<=2).
// Steady-state outstanding bytes/wave ~2KB x 8192 waves = ~16MB in flight.
// ---------------------------------------------------------------------------
__global__ __launch_bounds__(256)
void fused_kernel(const float* __restrict__ features,
                  const float* __restrict__ centers,
                  const int4*  __restrict__ meta,
                  const int*   __restrict__ order,
                  float* __restrict__ result,
                  float* __restrict__ out_centers) {
    const int wave = threadIdx.x >> 6;
    const int lane = threadIdx.x & 63;
    const int t    = lane & 31;                       // dim-quad index
    const int grp  = lane >> 5;                       // class within pair
    const int slot = blockIdx.x * 4 + wave;           // 0..8191
    const int stride = PBLOCKS * 4;                   // 8192

    int g = slot;                                     // first pair (< NPAIR)
    int4   m  = meta[2 * g + grp];
    float4 cv = ((const float4*)(centers + (size_t)(2 * g + grp) * D))[t];

    while (g < NPAIR) {
        // ---- prefetch next pair (loop-carried: stays in registers) ----
        const int gn = g + stride;
        int4   m_n  = make_int4(0, 0, 0, 0);
        float4 cv_n = make_float4(0.f, 0.f, 0.f, 0.f);
        if (gn < NPAIR) {
            const int cn = 2 * gn + grp;
            m_n  = meta[cn];
            cv_n = ((const float4*)(centers + (size_t)cn * D))[t];
        }

        // ---- consume current pair ----
        const int c     = 2 * g + grp;
        const int start = m.x;
        const int n     = m.y;

        float4 f0 = make_float4(0.f, 0.f, 0.f, 0.f);
        float4 f1 = make_float4(0.f, 0.f, 0.f, 0.f);
        if (n >= 1) f0 = ((const float4*)(features + (size_t)m.z * D))[t];
        if (n >= 2) f1 = ((const float4*)(features + (size_t)m.w * D))[t];

        float ax = 0.f, ay = 0.f, az = 0.f, aw = 0.f;
        if (n >= 1) {
            const float dx = f0.x - cv.x, dy = f0.y - cv.y;
            const float dz = f0.z - cv.z, dw = f0.w - cv.w;
            ax += dx; ay += dy; az += dz; aw += dw;
            const float ss = group_sum(dx * dx + dy * dy + dz * dz + dw * dw);
            if (t == 31) result[m.z] = ss;
        }
        if (n >= 2) {
            const float dx = f1.x - cv.x, dy = f1.y - cv.y;
            const float dz = f1.z - cv.z, dw = f1.w - cv.w;
            ax += dx; ay += dy; az += dz; aw += dw;
            const float ss = group_sum(dx * dx + dy * dy + dz * dz + dw * dw);
            if (t == 31) result[m.w] = ss;
        }
        // remainder (n>=3, ~15% of classes): paired order+feature loads
        for (int j = 2; j < n; j += 2) {
            const bool hasB = (j + 1) < n;
            const int bA = order[start + j];
            const int bB = order[min(start + j + 1, BATCH - 1)];
            const float4 fA = ((const float4*)(features + (size_t)bA * D))[t];
            float4 fB = make_float4(0.f, 0.f, 0.f, 0.f);
            if (hasB) fB = ((const float4*)(features + (size_t)bB * D))[t];
            {
                const float dx = fA.x - cv.x, dy = fA.y - cv.y;
                const float dz = fA.z - cv.z, dw = fA.w - cv.w;
                ax += dx; ay += dy; az += dz; aw += dw;
                const float ss = group_sum(dx * dx + dy * dy + dz * dz + dw * dw);
                if (t == 31) result[bA] = ss;
            }
            if (hasB) {
                const float dx = fB.x - cv.x, dy = fB.y - cv.y;
                const float dz = fB.z - cv.z, dw = fB.w - cv.w;
                ax += dx; ay += dy; az += dz; aw += dw;
                const float ss = group_sum(dx * dx + dy * dy + dz * dz + dw * dw);
                if (t == 31) result[bB] = ss;
            }
        }

        const float inv = ALPHA_C / (1.0f + (float)n);
        float4 o;
        o.x = cv.x + ax * inv;
        o.y = cv.y + ay * inv;
        o.z = cv.z + az * inv;
        o.w = cv.w + aw * inv;
        ((float4*)(out_centers + (size_t)c * D))[t] = o;

        // ---- rotate pipeline ----
        g = gn; m = m_n; cv = cv_n;
    }
}

// ---------------------------------------------------------------------------
extern "C" void kernel_launch(void* const* d_in, const int* in_sizes, int n_in,
                              void* d_out, int out_size, void* d_ws, size_t ws_size,
                              hipStream_t stream) {
    const float* features = (const float*)d_in[0];
    const int*   labels   = (const int*)d_in[1];
    const float* centers  = (const float*)d_in[2];

    float* result      = (float*)d_out;          // [BATCH]
    float* out_centers = result + BATCH;         // [C_CLASSES * D]

    // ws layout (ints): cnt_cur doubles as hist counts then scatter cursor.
    int*  ws        = (int*)d_ws;
    int*  cnt_cur   = ws;                        // [0, C)
    int4* meta      = (int4*)(ws + C_CLASSES);   // [C, 5C)  (400000B -> 16B aligned)
    int*  blockSums = ws + 5 * C_CLASSES;        // 64
    int*  order     = blockSums + 64;            // BATCH

    (void)hipMemsetAsync(cnt_cur, 0, C_CLASSES * sizeof(int), stream);

    hist_kernel   <<<BATCH / 256, 256, 0, stream>>>(labels, cnt_cur);
    scan1_kernel  <<<NB,          256, 0, stream>>>(cnt_cur, meta, blockSums);
    addoff_kernel <<<NB,          256, 0, stream>>>(meta, blockSums, cnt_cur);
    scatter_kernel<<<BATCH / 256, 256, 0, stream>>>(labels, cnt_cur, order, (int*)meta);

    fused_kernel  <<<PBLOCKS, 256, 0, stream>>>(
        features, centers, meta, order, result, out_centers);
}

// Round 11
// 65.250 us; speedup vs baseline: 1.0280x; 1.0280x over previous
//
#include <hip/hip_runtime.h>

#define ALPHA_C    0.5f
#define C_CLASSES  100000
#define D          128
#define BATCH      131072
#define CHUNK      2048
#define NB         ((C_CLASSES + CHUNK - 1) / CHUNK)   // 49 scan blocks
#define NPAIR      (C_CLASSES / 2)                     // 50000 class-pairs
#define PBLOCKS    2048                                // 8 blocks/CU -> 8192 waves

// ---------------------------------------------------------------------------
// DPP 32-lane group reduce (VALU-speed). row_shr 1,2,4,8 then bcast15:
// lane 31 = sum of lanes 0..31, lane 63 = sum of lanes 32..63.
// ---------------------------------------------------------------------------
template<int CTRL, int RMASK>
__device__ __forceinline__ float dpp_add(float x) {
    int v = __builtin_amdgcn_update_dpp(0, __float_as_int(x), CTRL, RMASK, 0xF, true);
    return x + __int_as_float(v);
}
__device__ __forceinline__ float group_sum(float ss) {
    ss = dpp_add<0x111, 0xF>(ss);   // row_shr:1
    ss = dpp_add<0x112, 0xF>(ss);   // row_shr:2
    ss = dpp_add<0x114, 0xF>(ss);   // row_shr:4
    ss = dpp_add<0x118, 0xF>(ss);   // row_shr:8
    ss = dpp_add<0x142, 0xA>(ss);   // row_bcast15 -> rows 1,3
    return ss;                      // lane31 / lane63 hold the 32-lane sums
}

// ---------------------------------------------------------------------------
// K1: label histogram, int4 label loads (1/4 the threads of R10)
// ---------------------------------------------------------------------------
__global__ void hist_kernel(const int4* __restrict__ labels4,
                            int* __restrict__ counts) {
    int i = blockIdx.x * blockDim.x + threadIdx.x;   // grid == BATCH/4 exactly
    const int4 l = labels4[i];
    atomicAdd(&counts[l.x], 1);
    atomicAdd(&counts[l.y], 1);
    atomicAdd(&counts[l.z], 1);
    atomicAdd(&counts[l.w], 1);
}

// ---------------------------------------------------------------------------
// K2 (merged scan1+scan2+addoff): per-chunk scan + decoupled lookback.
// 49 blocks, all co-resident (49 << 256 CUs) -> spin is deadlock-free.
// bflag/bsum are zeroed by the host-side memset each call (replay-safe).
// Writes finalized meta {start, n, 0, 0} and seeds cursor (== counts alias;
// each block reads its chunk's counts before overwriting them as cursor).
// ---------------------------------------------------------------------------
__global__ __launch_bounds__(256)
void scan_kernel(const int* __restrict__ counts,
                 int4* __restrict__ meta,
                 int* __restrict__ bsum,
                 int* __restrict__ bflag,
                 int* __restrict__ cursor) {
    __shared__ int sdata[256];
    __shared__ int s_off;
    const int tid  = threadIdx.x;
    const int blk  = blockIdx.x;
    const int base = blk * CHUNK + tid * 8;

    int v[8]; int s = 0;
    #pragma unroll
    for (int j = 0; j < 8; ++j) {
        int idx = base + j;
        v[j] = (idx < C_CLASSES) ? counts[idx] : 0;
        s += v[j];
    }
    sdata[tid] = s;
    __syncthreads();
    #pragma unroll
    for (int off = 1; off < 256; off <<= 1) {
        int t = (tid >= off) ? sdata[tid - off] : 0;
        __syncthreads();
        sdata[tid] += t;
        __syncthreads();
    }
    const int excl = sdata[tid] - s;                 // exclusive within chunk

    // publish this chunk's total (device-scope, flag after value)
    if (tid == 255) {
        atomicExch(&bsum[blk], sdata[255]);
        __threadfence();
        atomicExch(&bflag[blk], 1);
    }

    // lookback: thread t (< blk) waits for predecessor t's total
    if (tid < 64) {
        int pv = 0;
        if (tid < blk) {
            while (atomicAdd(&bflag[tid], 0) == 0) { }
            pv = atomicAdd(&bsum[tid], 0);
        }
        #pragma unroll
        for (int off = 32; off; off >>= 1) pv += __shfl_xor(pv, off);
        if (tid == 0) s_off = pv;
    }
    __syncthreads();
    const int off = s_off;

    int st = excl + off;
    #pragma unroll
    for (int j = 0; j < 8; ++j) {
        int idx = base + j;
        if (idx < C_CLASSES) {
            meta[idx]   = make_int4(st, v[j], 0, 0);
            cursor[idx] = st;                        // alias of counts: safe,
        }                                            // chunk-local, read-before-write
        st += v[j];
    }
}

// ---------------------------------------------------------------------------
// K3: scatter sample indices into class buckets; seed meta.z/.w with the
// first two sample indices of each class (removes the order-load hop for
// n<=2 classes, 85%). rel is unique per class -> no write race.
// ---------------------------------------------------------------------------
__global__ void scatter_kernel(const int* __restrict__ labels,
                               int* __restrict__ cursor,
                               int* __restrict__ order,
                               int* __restrict__ meta_raw) {   // int view of meta
    int b = blockIdx.x * blockDim.x + threadIdx.x;   // grid == BATCH exactly
    const int l   = labels[b];
    const int pos = atomicAdd(&cursor[l], 1);
    order[pos] = b;
    const int start = meta_raw[4 * l];               // finalized by scan_kernel
    const int rel   = pos - start;
    if (rel < 2) meta_raw[4 * l + 2 + rel] = b;      // .z or .w
}

// ---------------------------------------------------------------------------
// K4: PERSISTENT dim-major fused kernel (unchanged from R10 — measured at the
// random-row service-rate ceiling ~2.1-2.3 TB/s; structure-, concurrency- and
// residency-invariant across R8/R9/R10).
// ---------------------------------------------------------------------------
__global__ __launch_bounds__(256)
void fused_kernel(const float* __restrict__ features,
                  const float* __restrict__ centers,
                  const int4*  __restrict__ meta,
                  const int*   __restrict__ order,
                  float* __restrict__ result,
                  float* __restrict__ out_centers) {
    const int wave = threadIdx.x >> 6;
    const int lane = threadIdx.x & 63;
    const int t    = lane & 31;                       // dim-quad index
    const int grp  = lane >> 5;                       // class within pair
    const int slot = blockIdx.x * 4 + wave;           // 0..8191
    const int stride = PBLOCKS * 4;                   // 8192

    int g = slot;                                     // first pair (< NPAIR)
    int4   m  = meta[2 * g + grp];
    float4 cv = ((const float4*)(centers + (size_t)(2 * g + grp) * D))[t];

    while (g < NPAIR) {
        // ---- prefetch next pair (loop-carried: stays in registers) ----
        const int gn = g + stride;
        int4   m_n  = make_int4(0, 0, 0, 0);
        float4 cv_n = make_float4(0.f, 0.f, 0.f, 0.f);
        if (gn < NPAIR) {
            const int cn = 2 * gn + grp;
            m_n  = meta[cn];
            cv_n = ((const float4*)(centers + (size_t)cn * D))[t];
        }

        // ---- consume current pair ----
        const int c     = 2 * g + grp;
        const int start = m.x;
        const int n     = m.y;

        float4 f0 = make_float4(0.f, 0.f, 0.f, 0.f);
        float4 f1 = make_float4(0.f, 0.f, 0.f, 0.f);
        if (n >= 1) f0 = ((const float4*)(features + (size_t)m.z * D))[t];
        if (n >= 2) f1 = ((const float4*)(features + (size_t)m.w * D))[t];

        float ax = 0.f, ay = 0.f, az = 0.f, aw = 0.f;
        if (n >= 1) {
            const float dx = f0.x - cv.x, dy = f0.y - cv.y;
            const float dz = f0.z - cv.z, dw = f0.w - cv.w;
            ax += dx; ay += dy; az += dz; aw += dw;
            const float ss = group_sum(dx * dx + dy * dy + dz * dz + dw * dw);
            if (t == 31) result[m.z] = ss;
        }
        if (n >= 2) {
            const float dx = f1.x - cv.x, dy = f1.y - cv.y;
            const float dz = f1.z - cv.z, dw = f1.w - cv.w;
            ax += dx; ay += dy; az += dz; aw += dw;
            const float ss = group_sum(dx * dx + dy * dy + dz * dz + dw * dw);
            if (t == 31) result[m.w] = ss;
        }
        // remainder (n>=3, ~15% of classes): paired order+feature loads
        for (int j = 2; j < n; j += 2) {
            const bool hasB = (j + 1) < n;
            const int bA = order[start + j];
            const int bB = order[min(start + j + 1, BATCH - 1)];
            const float4 fA = ((const float4*)(features + (size_t)bA * D))[t];
            float4 fB = make_float4(0.f, 0.f, 0.f, 0.f);
            if (hasB) fB = ((const float4*)(features + (size_t)bB * D))[t];
            {
                const float dx = fA.x - cv.x, dy = fA.y - cv.y;
                const float dz = fA.z - cv.z, dw = fA.w - cv.w;
                ax += dx; ay += dy; az += dz; aw += dw;
                const float ss = group_sum(dx * dx + dy * dy + dz * dz + dw * dw);
                if (t == 31) result[bA] = ss;
            }
            if (hasB) {
                const float dx = fB.x - cv.x, dy = fB.y - cv.y;
                const float dz = fB.z - cv.z, dw = fB.w - cv.w;
                ax += dx; ay += dy; az += dz; aw += dw;
                const float ss = group_sum(dx * dx + dy * dy + dz * dz + dw * dw);
                if (t == 31) result[bB] = ss;
            }
        }

        const float inv = ALPHA_C / (1.0f + (float)n);
        float4 o;
        o.x = cv.x + ax * inv;
        o.y = cv.y + ay * inv;
        o.z = cv.z + az * inv;
        o.w = cv.w + aw * inv;
        ((float4*)(out_centers + (size_t)c * D))[t] = o;

        // ---- rotate pipeline ----
        g = gn; m = m_n; cv = cv_n;
    }
}

// ---------------------------------------------------------------------------
extern "C" void kernel_launch(void* const* d_in, const int* in_sizes, int n_in,
                              void* d_out, int out_size, void* d_ws, size_t ws_size,
                              hipStream_t stream) {
    const float* features = (const float*)d_in[0];
    const int*   labels   = (const int*)d_in[1];
    const float* centers  = (const float*)d_in[2];

    float* result      = (float*)d_out;          // [BATCH]
    float* out_centers = result + BATCH;         // [C_CLASSES * D]

    // ws layout (ints): [0,C) counts/cursor | [C,C+64) bflag | [C+64,C+128)
    // bsum | [C+128, 5C+128) meta (int4, 16B-aligned: (C+128)%4==0) | order.
    int*  ws      = (int*)d_ws;
    int*  cnt_cur = ws;                          // counts, later cursor
    int*  bflag   = ws + C_CLASSES;              // 64 (49 used)
    int*  bsum    = ws + C_CLASSES + 64;         // 64
    int4* meta    = (int4*)(ws + C_CLASSES + 128);
    int*  order   = ws + 5 * C_CLASSES + 128;    // BATCH

    // one memset covers counts + lookback flags/sums (replay-safe reset)
    (void)hipMemsetAsync(cnt_cur, 0, (C_CLASSES + 128) * sizeof(int), stream);

    hist_kernel   <<<BATCH / 1024, 256, 0, stream>>>((const int4*)labels, cnt_cur);
    scan_kernel   <<<NB,           256, 0, stream>>>(cnt_cur, meta, bsum, bflag, cnt_cur);
    scatter_kernel<<<BATCH / 256,  256, 0, stream>>>(labels, cnt_cur, order, (int*)meta);

    fused_kernel  <<<PBLOCKS, 256, 0, stream>>>(
        features, centers, meta, order, result, out_centers);
}